// Round 6
// baseline (118.145 us; speedup 1.0000x reference)
//
#include <hip/hip_runtime.h>
#include <math.h>

#define BB 4
#define CC 128
#define HH 256
#define WW 256
#define NN 4000
#define NPOS 8
#define KS 3
#define HWSZ (HH*WW)

#define SELU_ALPHA 1.6732632423543772f
#define SELU_SCALE 1.0507009873554805f
#define MAX_OFFSET 64.0f

typedef unsigned short ushort_t;
typedef short short8 __attribute__((ext_vector_type(8)));
typedef float f32x4 __attribute__((ext_vector_type(4)));
typedef unsigned short ushort4_t __attribute__((ext_vector_type(4)));

#define XT_ELEMS    ((size_t)BB*HH*WW*CC)        // 33,554,432 bf16
#define WSFBF_ELEMS ((size_t)CC*CC)              // 16,384 bf16
#define AGGT_ELEMS  ((size_t)NPOS*CC*CC)         // 131,072 bf16
#define W1T_ELEMS   ((size_t)16*CC*9)            // 18,432 bf16
#define WS_NEEDED   ((XT_ELEMS+WSFBF_ELEMS+AGGT_ELEMS+W1T_ELEMS)*sizeof(ushort_t))

__device__ __forceinline__ ushort_t f2bf(float f) {
    unsigned u = __builtin_bit_cast(unsigned, f);
    unsigned r = (u + 0x7FFFu + ((u >> 16) & 1u)) >> 16;
    return (ushort_t)r;
}
__device__ __forceinline__ float bf2f(ushort_t u) {
    return __builtin_bit_cast(float, ((unsigned)u) << 16);
}

// ---------------------------------------------------------------------------
// K0P: transpose x (B,C,H,W) f32 -> xt (B,H,W,C) bf16; tail blocks do weight prep.
__global__ __launch_bounds__(256) void k0p(
    const float* __restrict__ x, ushort_t* __restrict__ xt,
    const float* __restrict__ wsf, const float* __restrict__ agg,
    const float* __restrict__ w1,
    ushort_t* __restrict__ wsf_bf, ushort_t* __restrict__ aggT_bf,
    ushort_t* __restrict__ w1t_bf)
{
    int blk = blockIdx.x;
    const int t = threadIdx.x;
    if (blk >= BB * HH * 4) {
        int i = (blk - BB * HH * 4) * 256 + t;
        if (i < CC * CC) wsf_bf[i] = f2bf(wsf[i]);
        if (i < NPOS * CC * CC) {
            int p = i >> 14, d = (i >> 7) & 127, c = i & 127;
            aggT_bf[i] = f2bf(agg[(p << 14) + (c << 7) + d]);
        }
        if (i < 16 * 1152) {
            int o = i / 1152, e = i - o * 1152, k = e >> 7, c = e & 127;
            w1t_bf[i] = f2bf(w1[o * 1152 + c * 9 + k]);
        }
        return;
    }
    int xc = blk & 3, y = (blk >> 2) & 255, b = blk >> 10;
    int x0 = xc * 64;
    __shared__ ushort_t lds[64][136];

    const float* xb = x + (size_t)b * CC * HWSZ + (size_t)y * WW + x0;
    for (int v = t; v < 2048; v += 256) {
        int c = v >> 4, xo4 = v & 15;
        float4 val = *(const float4*)(xb + (size_t)c * HWSZ + xo4 * 4);
        lds[xo4*4+0][c] = f2bf(val.x);
        lds[xo4*4+1][c] = f2bf(val.y);
        lds[xo4*4+2][c] = f2bf(val.z);
        lds[xo4*4+3][c] = f2bf(val.w);
    }
    __syncthreads();
    ushort_t* outb = xt + ((size_t)b * HWSZ + (size_t)y * WW + x0) * CC;
    for (int v = t; v < 2048; v += 256) {
        int xo = v >> 5, c4 = v & 31;
        ushort4_t val;
        val[0] = lds[xo][c4*4+0];
        val[1] = lds[xo][c4*4+1];
        val[2] = lds[xo][c4*4+2];
        val[3] = lds[xo][c4*4+3];
        *(ushort4_t*)(outb + (size_t)xo * CC + c4 * 4) = val;
    }
}

// ---------------------------------------------------------------------------
// K14 fused, low-LDS (39.5 KB -> 4 blocks/CU):
// conv(MFMA, A from global) -> FC offsets -> bilinear -> fg=feats (bf16, swz
// (r&7)<<4) -> GEMM-C in-place (selu -> fg=g, swz ((row>>3)&7)<<4) ->
// GEMM-D(aggT) -> shfl-norm -> direct global stores.
__global__ __launch_bounds__(256, 4) void k14_fused(
    const ushort_t* __restrict__ xt, const float* __restrict__ kpts,
    const ushort_t* __restrict__ w1t_bf, const float* __restrict__ b1,
    const float* __restrict__ w2, const float* __restrict__ b2,
    const ushort_t* __restrict__ wsf_bf, const ushort_t* __restrict__ aggT_bf,
    float* __restrict__ out_desc, float* __restrict__ out_off)
{
    const int t    = threadIdx.x;
    const int wv   = t >> 6;
    const int lane = t & 63;
    const int m    = lane & 15;
    const int q    = lane >> 4;
    const int n0   = blockIdx.x * 16;
    const int b    = n0 / NN;
    const ushort_t* xb = xt + (size_t)b * HWSZ * CC;

    __shared__ ushort_t fg[CC * CC];      // feats then g (aliased, row-local)
    union PT {
        float partials[4][16][16];        // phase 1
        struct { int tapoff[128][4]; float tapw[128][4]; } tp;  // phases 2-3
    };
    __shared__ PT    upt;
    __shared__ float h1f[16][17];
    __shared__ float offs[16][16];
    __shared__ float kw[16][2];
    __shared__ int   cxy[16][2];
    __shared__ float wsum[4][16];
    __shared__ float rn[16];

    // ---- phase 0: keypoint coords + patch corners ----
    if (t < 16) {
        float kx = kpts[(size_t)(n0 + t) * 2 + 0];
        float ky = kpts[(size_t)(n0 + t) * 2 + 1];
        float kwx = (kx * 0.5f + 0.5f) * (float)(WW - 1);
        float kwy = (ky * 0.5f + 0.5f) * (float)(HH - 1);
        kw[t][0] = kwx; kw[t][1] = kwy;
        int rcx = (int)kwx, rcy = (int)kwy;
        int cx = (int)truncf((float)rcx - 0.5f);
        int cy = (int)truncf((float)rcy - 0.5f);
        cxy[t][0] = min(max(cx, 0), WW - 1 - KS);
        cxy[t][1] = min(max(cy, 0), HH - 1 - KS);
    }
    __syncthreads();

    // ---- phase 1: conv via MFMA, A-fragments directly from global xt ----
    {
        int px0 = cxy[m][0], py0 = cxy[m][1];
        f32x4 hacc = {0.f, 0.f, 0.f, 0.f};
        const ushort_t* brow = w1t_bf + m * 1152 + wv * 288 + q * 8;
        #pragma unroll
        for (int kk = 0; kk < 9; ++kk) {
            int e = wv * 288 + kk * 32 + q * 8;
            int k = e >> 7, c = e & 127;
            int kd = k / 3, kx2 = k - kd * 3;
            const ushort_t* src = xb + ((size_t)((py0 + kd) * WW + px0 + kx2)) * CC + c;
            short8 a   = *(const short8*)src;
            short8 bfr = *(const short8*)(brow + kk * 32);
            hacc = __builtin_amdgcn_mfma_f32_16x16x32_bf16(a, bfr, hacc, 0, 0, 0);
        }
        #pragma unroll
        for (int r = 0; r < 4; ++r) upt.partials[wv][q * 4 + r][m] = hacc[r];
    }
    __syncthreads();
    {   // reduce K-partials + bias + relu
        int kp = t >> 4, o = t & 15;
        float h = upt.partials[0][kp][o] + upt.partials[1][kp][o]
                + upt.partials[2][kp][o] + upt.partials[3][kp][o] + b1[o];
        h1f[kp][o] = fmaxf(h, 0.f);
    }
    __syncthreads();
    {   // FC: off[kp][j] = clip(h1 . w2[j] + b2[j])
        int kp = t >> 4, j = t & 15;
        float s = b2[j];
        #pragma unroll
        for (int o = 0; o < 16; ++o) s += h1f[kp][o] * w2[j * 16 + o];
        s = fminf(fmaxf(s, -MAX_OFFSET), MAX_OFFSET);
        offs[kp][j] = s;
        int p = j & 7, comp = j >> 3;
        out_off[((size_t)(n0 + kp) * 8 + p) * 2 + comp] = s;
    }
    __syncthreads();

    // ---- phase 2: tap coords/weights once per (kp,p) (taps alias partials) ----
    if (t < 128) {
        int kp = t >> 3, p = t & 7;
        float px = kw[kp][0] + offs[kp][p];
        float py = kw[kp][1] + offs[kp][8 + p];
        float x0f = floorf(px), y0f = floorf(py);
        int x0 = (int)x0f, y0 = (int)y0f;
        float wx1 = px - x0f, wx0 = 1.f - wx1;
        float wy1 = py - y0f, wy0 = 1.f - wy1;
        int x0c = min(max(x0, 0), WW - 1);
        int x1c = min(max(x0 + 1, 0), WW - 1);
        int y0c = min(max(y0, 0), HH - 1);
        int y1c = min(max(y0 + 1, 0), HH - 1);
        float vx0 = (x0 >= 0 && x0 < WW) ? 1.f : 0.f;
        float vx1 = (x0 + 1 >= 0 && x0 + 1 < WW) ? 1.f : 0.f;
        float vy0 = (y0 >= 0 && y0 < HH) ? 1.f : 0.f;
        float vy1 = (y0 + 1 >= 0 && y0 + 1 < HH) ? 1.f : 0.f;
        upt.tp.tapoff[t][0] = (y0c * WW + x0c) * CC;
        upt.tp.tapoff[t][1] = (y0c * WW + x1c) * CC;
        upt.tp.tapoff[t][2] = (y1c * WW + x0c) * CC;
        upt.tp.tapoff[t][3] = (y1c * WW + x1c) * CC;
        upt.tp.tapw[t][0] = wx0 * wy0 * vx0 * vy0;
        upt.tp.tapw[t][1] = wx1 * wy0 * vx1 * vy0;
        upt.tp.tapw[t][2] = wx0 * wy1 * vx0 * vy1;
        upt.tp.tapw[t][3] = wx1 * wy1 * vx1 * vy1;
    }
    __syncthreads();

    // ---- phase 3: bilinear -> fg (bf16, swizzled, bank-even interleave) ----
    {
        int pair = t >> 1, half = t & 1;       // row r = pair = kp*8+p
        const ushort_t* s0 = xb + upt.tp.tapoff[pair][0];
        const ushort_t* s1 = xb + upt.tp.tapoff[pair][1];
        const ushort_t* s2 = xb + upt.tp.tapoff[pair][2];
        const ushort_t* s3 = xb + upt.tp.tapoff[pair][3];
        float w00 = upt.tp.tapw[pair][0], w01 = upt.tp.tapw[pair][1];
        float w10 = upt.tp.tapw[pair][2], w11 = upt.tp.tapw[pair][3];
        unsigned rbase = (unsigned)(pair * 256);
        unsigned key   = ((unsigned)(pair & 7)) << 4;
        #pragma unroll
        for (int i = 0; i < 16; ++i) {
            int c = i * 8 + half * 4;          // interleaved: banks spread evenly
            ushort4_t t0 = *(const ushort4_t*)(s0 + c);
            ushort4_t t1 = *(const ushort4_t*)(s1 + c);
            ushort4_t t2 = *(const ushort4_t*)(s2 + c);
            ushort4_t t3 = *(const ushort4_t*)(s3 + c);
            ushort4_t r4;
            #pragma unroll
            for (int j = 0; j < 4; ++j) {
                float v = bf2f(t0[j]) * w00 + bf2f(t1[j]) * w01
                        + bf2f(t2[j]) * w10 + bf2f(t3[j]) * w11;
                r4[j] = f2bf(v);
            }
            unsigned byte = (rbase + (unsigned)c * 2) ^ key;
            *(ushort4_t*)((char*)fg + byte) = r4;
        }
    }
    __syncthreads();

    // ---- phase 4: GEMM-C (fg(feats) x wsf^T -> selu -> fg(g), in-place) ----
    for (int rti = 0; rti < 2; ++rti) {
        int rt = wv * 2 + rti;
        int r  = rt * 16 + m;
        unsigned key = ((unsigned)(r & 7)) << 4;
        short8 afr[4];
        #pragma unroll
        for (int kk = 0; kk < 4; ++kk) {
            unsigned byte = ((unsigned)(r * 256 + q * 16 + kk * 64)) ^ key;
            afr[kk] = *(const short8*)((const char*)fg + byte);
        }
        for (int ct = 0; ct < 8; ++ct) {
            const ushort_t* brow = wsf_bf + (ct * 16 + m) * CC + q * 8;
            f32x4 acc = {0.f, 0.f, 0.f, 0.f};
            #pragma unroll
            for (int kk = 0; kk < 4; ++kk) {
                short8 bfr = *(const short8*)(brow + kk * 32);
                acc = __builtin_amdgcn_mfma_f32_16x16x32_bf16(afr[kk], bfr, acc, 0, 0, 0);
            }
            #pragma unroll
            for (int rr = 0; rr < 4; ++rr) {
                float s = acc[rr];
                s = (s > 0.f) ? (SELU_SCALE * s)
                              : (SELU_SCALE * SELU_ALPHA * (expf(s) - 1.f));
                int row = rt * 16 + q * 4 + rr;     // same 16-row block as afr rows
                int col = ct * 16 + m;
                unsigned byte = ((unsigned)(row * 256 + col * 2))
                              ^ (((unsigned)((row >> 3) & 7)) << 4);
                *(ushort_t*)((char*)fg + byte) = f2bf(s);
            }
        }
    }
    __syncthreads();

    // ---- phase 5: GEMM-D (fg(g) x aggT) ----
    f32x4 acc2[2];
    acc2[0] = (f32x4){0.f, 0.f, 0.f, 0.f};
    acc2[1] = (f32x4){0.f, 0.f, 0.f, 0.f};
    const int ctbase = wv * 2;
    for (int kk = 0; kk < 32; ++kk) {
        int p    = kk >> 2;
        int rowA = m * 8 + p;
        unsigned byte = ((unsigned)(rowA * 256 + (kk & 3) * 64 + q * 16))
                      ^ (((unsigned)((rowA >> 3) & 7)) << 4);
        short8 afr = *(const short8*)((const char*)fg + byte);
        #pragma unroll
        for (int i = 0; i < 2; ++i) {
            int ct = ctbase + i;
            const ushort_t* brow = aggT_bf + (size_t)(p * CC + ct * 16 + m) * CC
                                 + (kk & 3) * 32 + q * 8;
            short8 bfr = *(const short8*)brow;
            acc2[i] = __builtin_amdgcn_mfma_f32_16x16x32_bf16(afr, bfr, acc2[i], 0, 0, 0);
        }
    }

    // ---- shfl-reduce L2 norm + direct normalized stores ----
    {
        float ss[4];
        #pragma unroll
        for (int rr = 0; rr < 4; ++rr)
            ss[rr] = acc2[0][rr] * acc2[0][rr] + acc2[1][rr] * acc2[1][rr];
        #pragma unroll
        for (int mask = 1; mask <= 8; mask <<= 1) {
            #pragma unroll
            for (int rr = 0; rr < 4; ++rr) ss[rr] += __shfl_xor(ss[rr], mask);
        }
        if (m == 0) {
            #pragma unroll
            for (int rr = 0; rr < 4; ++rr) wsum[wv][q * 4 + rr] = ss[rr];
        }
    }
    __syncthreads();
    if (t < 16) {
        float tot = wsum[0][t] + wsum[1][t] + wsum[2][t] + wsum[3][t];
        rn[t] = 1.0f / fmaxf(sqrtf(tot), 1e-12f);
    }
    __syncthreads();
    {
        #pragma unroll
        for (int i = 0; i < 2; ++i) {
            int col = (ctbase + i) * 16 + m;
            #pragma unroll
            for (int rr = 0; rr < 4; ++rr) {
                int n = q * 4 + rr;
                out_desc[(size_t)(n0 + n) * CC + col] = acc2[i][rr] * rn[n];
            }
        }
    }
}

// ---------------------------------------------------------------------------
// Fallback: original fused baseline (used only if ws is too small).
__global__ __launch_bounds__(256, 4) void sddh_baseline(
    const float* __restrict__ x, const float* __restrict__ keypoints,
    const float* __restrict__ w1, const float* __restrict__ b1,
    const float* __restrict__ w2, const float* __restrict__ b2,
    const float* __restrict__ wsf, const float* __restrict__ agg,
    float* __restrict__ out_desc, float* __restrict__ out_off)
{
    const int bn = blockIdx.x;
    const int b  = bn / NN;
    const int t  = threadIdx.x;
    const float* xi = x + (size_t)b * CC * HWSZ;

    __shared__ float patch[CC * 9];
    __shared__ float conv_part[16][17];
    __shared__ float h1s[16];
    __shared__ float offs[16];
    __shared__ float feats[CC][NPOS];
    __shared__ float cpart2[CC][NPOS];
    __shared__ float g[CC][NPOS];
    __shared__ float dpart[CC];
    __shared__ float desc[CC];
    __shared__ float sq[128];
    __shared__ float kxy[2];

    if (t == 0) {
        float kx = keypoints[(size_t)bn * 2 + 0];
        float ky = keypoints[(size_t)bn * 2 + 1];
        kxy[0] = (kx * 0.5f + 0.5f) * (float)(WW - 1);
        kxy[1] = (ky * 0.5f + 0.5f) * (float)(HH - 1);
    }
    __syncthreads();
    const float kwx = kxy[0], kwy = kxy[1];
    const int rcx = (int)kwx, rcy = (int)kwy;
    int cx = (int)truncf((float)rcx - 0.5f);
    int cy = (int)truncf((float)rcy - 0.5f);
    cx = min(max(cx, 0), WW - 1 - KS);
    cy = min(max(cy, 0), HH - 1 - KS);

    for (int e = t; e < CC * 9; e += 256) {
        int c = e / 9, k = e % 9;
        int dy = k / 3, dx = k % 3;
        patch[e] = xi[(size_t)c * HWSZ + (cy + dy) * WW + (cx + dx)];
    }
    __syncthreads();
    {
        int o = t & 15, j = t >> 4;
        float acc = 0.f;
        const float* wo = w1 + o * (CC * 9);
        for (int e = j; e < CC * 9; e += 16) acc += patch[e] * wo[e];
        conv_part[o][j] = acc;
    }
    __syncthreads();
    if (t < 16) {
        float s = b1[t];
        #pragma unroll
        for (int j = 0; j < 16; j++) s += conv_part[t][j];
        h1s[t] = fmaxf(s, 0.f);
    }
    __syncthreads();
    if (t < 16) {
        float s = b2[t];
        #pragma unroll
        for (int k = 0; k < 16; k++) s += h1s[k] * w2[t * 16 + k];
        s = fminf(fmaxf(s, -MAX_OFFSET), MAX_OFFSET);
        offs[t] = s;
        int idx = (t < 8) ? (bn * 16 + t * 2) : (bn * 16 + (t - 8) * 2 + 1);
        out_off[idx] = s;
    }
    __syncthreads();

    for (int e = t; e < CC * NPOS; e += 256) {
        int c = e & 127, p = e >> 7;
        float px = kwx + offs[p];
        float py = kwy + offs[8 + p];
        float x0f = floorf(px), y0f = floorf(py);
        int x0 = (int)x0f, y0 = (int)y0f;
        float wx1 = px - x0f, wx0 = 1.f - wx1;
        float wy1 = py - y0f, wy0 = 1.f - wy1;
        const float* xc = xi + (size_t)c * HWSZ;
        int x0c = min(max(x0, 0), WW - 1);
        int x1c = min(max(x0 + 1, 0), WW - 1);
        int y0c = min(max(y0, 0), HH - 1);
        int y1c = min(max(y0 + 1, 0), HH - 1);
        float vx0 = (x0 >= 0 && x0 < WW) ? 1.f : 0.f;
        float vx1 = (x0 + 1 >= 0 && x0 + 1 < WW) ? 1.f : 0.f;
        float vy0 = (y0 >= 0 && y0 < HH) ? 1.f : 0.f;
        float vy1 = (y0 + 1 >= 0 && y0 + 1 < HH) ? 1.f : 0.f;
        float v = 0.f;
        v += xc[y0c * WW + x0c] * (wx0 * wy0) * (vx0 * vy0);
        v += xc[y0c * WW + x1c] * (wx1 * wy0) * (vx1 * vy0);
        v += xc[y1c * WW + x0c] * (wx0 * wy1) * (vx0 * vy1);
        v += xc[y1c * WW + x1c] * (wx1 * wy1) * (vx1 * vy1);
        feats[c][p] = v;
    }
    __syncthreads();
    {
        int d = t & 127, chalf = t >> 7;
        float acc[NPOS];
        #pragma unroll
        for (int p = 0; p < NPOS; p++) acc[p] = 0.f;
        const float* wrow = wsf + d * CC;
        int c0 = chalf * 64;
        for (int c = c0; c < c0 + 64; c++) {
            float wv = wrow[c];
            #pragma unroll
            for (int p = 0; p < NPOS; p++) acc[p] += feats[c][p] * wv;
        }
        if (chalf) {
            #pragma unroll
            for (int p = 0; p < NPOS; p++) cpart2[d][p] = acc[p];
        }
        __syncthreads();
        if (!chalf) {
            #pragma unroll
            for (int p = 0; p < NPOS; p++) {
                float s = acc[p] + cpart2[d][p];
                s = (s > 0.f) ? (SELU_SCALE * s)
                              : (SELU_SCALE * SELU_ALPHA * (expf(s) - 1.f));
                g[d][p] = s;
            }
        }
    }
    __syncthreads();
    {
        int d = t & 127, half = t >> 7;
        float acc = 0.f;
        int p0 = half * 4;
        for (int p = p0; p < p0 + 4; p++) {
            const float* ap = agg + (size_t)p * CC * CC;
            for (int e = 0; e < CC; e++) acc += g[e][p] * ap[e * CC + d];
        }
        if (half) dpart[d] = acc;
        __syncthreads();
        if (!half) {
            float v = acc + dpart[d];
            desc[d] = v;
            sq[d] = v * v;
        }
    }
    __syncthreads();
    if (t < 64) sq[t] += sq[t + 64]; __syncthreads();
    if (t < 32) sq[t] += sq[t + 32]; __syncthreads();
    if (t < 16) sq[t] += sq[t + 16]; __syncthreads();
    if (t < 8)  sq[t] += sq[t + 8];  __syncthreads();
    if (t < 4)  sq[t] += sq[t + 4];  __syncthreads();
    if (t < 2)  sq[t] += sq[t + 2];  __syncthreads();
    if (t == 0) sq[0] = fmaxf(sqrtf(sq[0] + sq[1]), 1e-12f);
    __syncthreads();
    if (t < 128) out_desc[(size_t)bn * CC + t] = desc[t] / sq[0];
}

// ---------------------------------------------------------------------------
extern "C" void kernel_launch(void* const* d_in, const int* in_sizes, int n_in,
                              void* d_out, int out_size, void* d_ws, size_t ws_size,
                              hipStream_t stream) {
    const float* x    = (const float*)d_in[0];
    const float* kpts = (const float*)d_in[1];
    const float* w1   = (const float*)d_in[2];
    const float* b1   = (const float*)d_in[3];
    const float* w2   = (const float*)d_in[4];
    const float* b2   = (const float*)d_in[5];
    const float* wsf  = (const float*)d_in[6];
    const float* agg  = (const float*)d_in[7];

    float* out_desc = (float*)d_out;
    float* out_off  = (float*)d_out + (size_t)BB * NN * CC;

    if (ws_size < WS_NEEDED) {
        hipLaunchKernelGGL(sddh_baseline, dim3(BB * NN), dim3(256), 0, stream,
                           x, kpts, w1, b1, w2, b2, wsf, agg, out_desc, out_off);
        return;
    }

    ushort_t* xt      = (ushort_t*)d_ws;
    ushort_t* wsf_bf  = xt + XT_ELEMS;
    ushort_t* aggT_bf = wsf_bf + WSFBF_ELEMS;
    ushort_t* w1t_bf  = aggT_bf + AGGT_ELEMS;

    hipLaunchKernelGGL(k0p, dim3(BB * HH * 4 + 512), dim3(256), 0, stream,
                       x, xt, wsf, agg, w1, wsf_bf, aggT_bf, w1t_bf);
    hipLaunchKernelGGL(k14_fused, dim3(BB * NN / 16), dim3(256), 0, stream,
                       xt, kpts, w1t_bf, b1, w2, b2, wsf_bf, aggT_bf,
                       out_desc, out_off);
}

// Round 8
// 112.233 us; speedup vs baseline: 1.0527x; 1.0527x over previous
//
#include <hip/hip_runtime.h>
#include <math.h>

#define BB 4
#define CC 128
#define HH 256
#define WW 256
#define NN 4000
#define NPOS 8
#define KS 3
#define HWSZ (HH*WW)

#define SELU_ALPHA 1.6732632423543772f
#define SELU_SCALE 1.0507009873554805f
#define MAX_OFFSET 64.0f

typedef unsigned short ushort_t;
typedef short short8 __attribute__((ext_vector_type(8)));
typedef float f32x4 __attribute__((ext_vector_type(4)));
typedef unsigned short ushort4_t __attribute__((ext_vector_type(4)));
typedef unsigned short ushort8_t __attribute__((ext_vector_type(8)));

#define XT_ELEMS    ((size_t)BB*HH*WW*CC)        // 33,554,432 bf16
#define WSFBF_ELEMS ((size_t)CC*CC)              // 16,384 bf16
#define AGGT_ELEMS  ((size_t)NPOS*CC*CC)         // 131,072 bf16
#define W1T_ELEMS   ((size_t)16*CC*9)            // 18,432 bf16
#define WS_NEEDED   ((XT_ELEMS+WSFBF_ELEMS+AGGT_ELEMS+W1T_ELEMS)*sizeof(ushort_t))

__device__ __forceinline__ ushort_t f2bf(float f) {
    unsigned u = __builtin_bit_cast(unsigned, f);
    unsigned r = (u + 0x7FFFu + ((u >> 16) & 1u)) >> 16;
    return (ushort_t)r;
}
__device__ __forceinline__ float bf2f(ushort_t u) {
    return __builtin_bit_cast(float, ((unsigned)u) << 16);
}

// ---------------------------------------------------------------------------
// K0P: transpose x (B,C,H,W) f32 -> xt (B,H,W,C) bf16; tail blocks do weight prep.
__global__ __launch_bounds__(256) void k0p(
    const float* __restrict__ x, ushort_t* __restrict__ xt,
    const float* __restrict__ wsf, const float* __restrict__ agg,
    const float* __restrict__ w1,
    ushort_t* __restrict__ wsf_bf, ushort_t* __restrict__ aggT_bf,
    ushort_t* __restrict__ w1t_bf)
{
    int blk = blockIdx.x;
    const int t = threadIdx.x;
    if (blk >= BB * HH * 4) {
        int i = (blk - BB * HH * 4) * 256 + t;
        if (i < CC * CC) wsf_bf[i] = f2bf(wsf[i]);
        if (i < NPOS * CC * CC) {
            int p = i >> 14, d = (i >> 7) & 127, c = i & 127;
            aggT_bf[i] = f2bf(agg[(p << 14) + (c << 7) + d]);
        }
        if (i < 16 * 1152) {
            int o = i / 1152, e = i - o * 1152, k = e >> 7, c = e & 127;
            w1t_bf[i] = f2bf(w1[o * 1152 + c * 9 + k]);
        }
        return;
    }
    int xc = blk & 3, y = (blk >> 2) & 255, b = blk >> 10;
    int x0 = xc * 64;
    __shared__ ushort_t lds[64][136];

    const float* xb = x + (size_t)b * CC * HWSZ + (size_t)y * WW + x0;
    for (int v = t; v < 2048; v += 256) {
        int c = v >> 4, xo4 = v & 15;
        float4 val = *(const float4*)(xb + (size_t)c * HWSZ + xo4 * 4);
        lds[xo4*4+0][c] = f2bf(val.x);
        lds[xo4*4+1][c] = f2bf(val.y);
        lds[xo4*4+2][c] = f2bf(val.z);
        lds[xo4*4+3][c] = f2bf(val.w);
    }
    __syncthreads();
    ushort_t* outb = xt + ((size_t)b * HWSZ + (size_t)y * WW + x0) * CC;
    for (int v = t; v < 2048; v += 256) {
        int xo = v >> 5, c4 = v & 31;
        ushort4_t val;
        val[0] = lds[xo][c4*4+0];
        val[1] = lds[xo][c4*4+1];
        val[2] = lds[xo][c4*4+2];
        val[3] = lds[xo][c4*4+3];
        *(ushort4_t*)(outb + (size_t)xo * CC + c4 * 4) = val;
    }
}

// ---------------------------------------------------------------------------
// K14 fused (R6 base, phase-3 lane mapping changed to 16-lane coalesced):
// conv(MFMA, A from global) -> FC offsets -> taps -> bilinear (16 lanes per
// (kp,p), 256B coalesced tap rows) -> fg=feats (bf16, swz (r&7)<<4) ->
// GEMM-C in-place (selu -> fg=g) -> GEMM-D -> shfl-norm -> direct stores.
__global__ __launch_bounds__(256, 4) void k14_fused(
    const ushort_t* __restrict__ xt, const float* __restrict__ kpts,
    const ushort_t* __restrict__ w1t_bf, const float* __restrict__ b1,
    const float* __restrict__ w2, const float* __restrict__ b2,
    const ushort_t* __restrict__ wsf_bf, const ushort_t* __restrict__ aggT_bf,
    float* __restrict__ out_desc, float* __restrict__ out_off)
{
    const int t    = threadIdx.x;
    const int wv   = t >> 6;
    const int lane = t & 63;
    const int m    = lane & 15;
    const int q    = lane >> 4;
    const int n0   = blockIdx.x * 16;
    const int b    = n0 / NN;
    const ushort_t* xb = xt + (size_t)b * HWSZ * CC;

    __shared__ ushort_t fg[CC * CC];      // feats then g (aliased, row-local)
    union PT {
        float partials[4][16][16];        // phase 1
        struct { int tapoff[128][4]; float tapw[128][4]; } tp;  // phases 2-3
    };
    __shared__ PT    upt;
    __shared__ float h1f[16][17];
    __shared__ float offs[16][16];
    __shared__ float kw[16][2];
    __shared__ int   cxy[16][2];
    __shared__ float wsum[4][16];
    __shared__ float rn[16];

    // ---- phase 0: keypoint coords + patch corners ----
    if (t < 16) {
        float kx = kpts[(size_t)(n0 + t) * 2 + 0];
        float ky = kpts[(size_t)(n0 + t) * 2 + 1];
        float kwx = (kx * 0.5f + 0.5f) * (float)(WW - 1);
        float kwy = (ky * 0.5f + 0.5f) * (float)(HH - 1);
        kw[t][0] = kwx; kw[t][1] = kwy;
        int rcx = (int)kwx, rcy = (int)kwy;
        int cx = (int)truncf((float)rcx - 0.5f);
        int cy = (int)truncf((float)rcy - 0.5f);
        cxy[t][0] = min(max(cx, 0), WW - 1 - KS);
        cxy[t][1] = min(max(cy, 0), HH - 1 - KS);
    }
    __syncthreads();

    // ---- phase 1: conv via MFMA, A-fragments directly from global xt ----
    {
        int px0 = cxy[m][0], py0 = cxy[m][1];
        f32x4 hacc = {0.f, 0.f, 0.f, 0.f};
        const ushort_t* brow = w1t_bf + m * 1152 + wv * 288 + q * 8;
        #pragma unroll
        for (int kk = 0; kk < 9; ++kk) {
            int e = wv * 288 + kk * 32 + q * 8;
            int k = e >> 7, c = e & 127;
            int kd = k / 3, kx2 = k - kd * 3;
            const ushort_t* src = xb + ((size_t)((py0 + kd) * WW + px0 + kx2)) * CC + c;
            short8 a   = *(const short8*)src;
            short8 bfr = *(const short8*)(brow + kk * 32);
            hacc = __builtin_amdgcn_mfma_f32_16x16x32_bf16(a, bfr, hacc, 0, 0, 0);
        }
        #pragma unroll
        for (int r = 0; r < 4; ++r) upt.partials[wv][q * 4 + r][m] = hacc[r];
    }
    __syncthreads();
    {   // reduce K-partials + bias + relu
        int kp = t >> 4, o = t & 15;
        float h = upt.partials[0][kp][o] + upt.partials[1][kp][o]
                + upt.partials[2][kp][o] + upt.partials[3][kp][o] + b1[o];
        h1f[kp][o] = fmaxf(h, 0.f);
    }
    __syncthreads();
    {   // FC: off[kp][j] = clip(h1 . w2[j] + b2[j])
        int kp = t >> 4, j = t & 15;
        float s = b2[j];
        #pragma unroll
        for (int o = 0; o < 16; ++o) s += h1f[kp][o] * w2[j * 16 + o];
        s = fminf(fmaxf(s, -MAX_OFFSET), MAX_OFFSET);
        offs[kp][j] = s;
        int p = j & 7, comp = j >> 3;
        out_off[((size_t)(n0 + kp) * 8 + p) * 2 + comp] = s;
    }
    __syncthreads();

    // ---- phase 2: tap coords/weights once per (kp,p) (taps alias partials) ----
    if (t < 128) {
        int kp = t >> 3, p = t & 7;
        float px = kw[kp][0] + offs[kp][p];
        float py = kw[kp][1] + offs[kp][8 + p];
        float x0f = floorf(px), y0f = floorf(py);
        int x0 = (int)x0f, y0 = (int)y0f;
        float wx1 = px - x0f, wx0 = 1.f - wx1;
        float wy1 = py - y0f, wy0 = 1.f - wy1;
        int x0c = min(max(x0, 0), WW - 1);
        int x1c = min(max(x0 + 1, 0), WW - 1);
        int y0c = min(max(y0, 0), HH - 1);
        int y1c = min(max(y0 + 1, 0), HH - 1);
        float vx0 = (x0 >= 0 && x0 < WW) ? 1.f : 0.f;
        float vx1 = (x0 + 1 >= 0 && x0 + 1 < WW) ? 1.f : 0.f;
        float vy0 = (y0 >= 0 && y0 < HH) ? 1.f : 0.f;
        float vy1 = (y0 + 1 >= 0 && y0 + 1 < HH) ? 1.f : 0.f;
        upt.tp.tapoff[t][0] = (y0c * WW + x0c) * CC;
        upt.tp.tapoff[t][1] = (y0c * WW + x1c) * CC;
        upt.tp.tapoff[t][2] = (y1c * WW + x0c) * CC;
        upt.tp.tapoff[t][3] = (y1c * WW + x1c) * CC;
        upt.tp.tapw[t][0] = wx0 * wy0 * vx0 * vy0;
        upt.tp.tapw[t][1] = wx1 * wy0 * vx1 * vy0;
        upt.tp.tapw[t][2] = wx0 * wy1 * vx0 * vy1;
        upt.tp.tapw[t][3] = wx1 * wy1 * vx1 * vy1;
    }
    __syncthreads();

    // ---- phase 3: bilinear, 16 lanes per (kp,p): 256B coalesced tap rows ----
    {
        const int grp = t >> 4;        // 16 groups of 16 lanes
        const int cl  = t & 15;        // channel octet
        #pragma unroll
        for (int it = 0; it < 8; ++it) {
            int pair = it * 16 + grp;  // row r = pair = kp*8+p
            const int*   to = upt.tp.tapoff[pair];
            const float* tw = upt.tp.tapw[pair];
            ushort8_t t0 = *(const ushort8_t*)(xb + to[0] + cl * 8);
            ushort8_t t1 = *(const ushort8_t*)(xb + to[1] + cl * 8);
            ushort8_t t2 = *(const ushort8_t*)(xb + to[2] + cl * 8);
            ushort8_t t3 = *(const ushort8_t*)(xb + to[3] + cl * 8);
            float w00 = tw[0], w01 = tw[1], w10 = tw[2], w11 = tw[3];
            ushort8_t out;
            #pragma unroll
            for (int j = 0; j < 8; ++j) {
                float v = bf2f(t0[j]) * w00;
                v += bf2f(t1[j]) * w01;
                v += bf2f(t2[j]) * w10;
                v += bf2f(t3[j]) * w11;
                out[j] = f2bf(v);
            }
            unsigned byte = ((unsigned)(pair * 256 + cl * 16))
                          ^ (((unsigned)(pair & 7)) << 4);
            *(ushort8_t*)((char*)fg + byte) = out;
        }
    }
    __syncthreads();

    // ---- phase 4: GEMM-C (fg(feats) x wsf^T -> selu -> fg(g), in-place) ----
    for (int rti = 0; rti < 2; ++rti) {
        int rt = wv * 2 + rti;
        int r  = rt * 16 + m;
        unsigned key = ((unsigned)(r & 7)) << 4;
        short8 afr[4];
        #pragma unroll
        for (int kk = 0; kk < 4; ++kk) {
            unsigned byte = ((unsigned)(r * 256 + q * 16 + kk * 64)) ^ key;
            afr[kk] = *(const short8*)((const char*)fg + byte);
        }
        for (int ct = 0; ct < 8; ++ct) {
            const ushort_t* brow = wsf_bf + (ct * 16 + m) * CC + q * 8;
            f32x4 acc = {0.f, 0.f, 0.f, 0.f};
            #pragma unroll
            for (int kk = 0; kk < 4; ++kk) {
                short8 bfr = *(const short8*)(brow + kk * 32);
                acc = __builtin_amdgcn_mfma_f32_16x16x32_bf16(afr[kk], bfr, acc, 0, 0, 0);
            }
            #pragma unroll
            for (int rr = 0; rr < 4; ++rr) {
                float s = acc[rr];
                s = (s > 0.f) ? (SELU_SCALE * s)
                              : (SELU_SCALE * SELU_ALPHA * (expf(s) - 1.f));
                int row = rt * 16 + q * 4 + rr;     // same 16-row block as afr rows
                int col = ct * 16 + m;
                unsigned byte = ((unsigned)(row * 256 + col * 2))
                              ^ (((unsigned)((row >> 3) & 7)) << 4);
                *(ushort_t*)((char*)fg + byte) = f2bf(s);
            }
        }
    }
    __syncthreads();

    // ---- phase 5: GEMM-D (fg(g) x aggT) ----
    f32x4 acc2[2];
    acc2[0] = (f32x4){0.f, 0.f, 0.f, 0.f};
    acc2[1] = (f32x4){0.f, 0.f, 0.f, 0.f};
    const int ctbase = wv * 2;
    for (int kk = 0; kk < 32; ++kk) {
        int p    = kk >> 2;
        int rowA = m * 8 + p;
        unsigned byte = ((unsigned)(rowA * 256 + (kk & 3) * 64 + q * 16))
                      ^ (((unsigned)((rowA >> 3) & 7)) << 4);
        short8 afr = *(const short8*)((const char*)fg + byte);
        #pragma unroll
        for (int i = 0; i < 2; ++i) {
            int ct = ctbase + i;
            const ushort_t* brow = aggT_bf + (size_t)(p * CC + ct * 16 + m) * CC
                                 + (kk & 3) * 32 + q * 8;
            short8 bfr = *(const short8*)brow;
            acc2[i] = __builtin_amdgcn_mfma_f32_16x16x32_bf16(afr, bfr, acc2[i], 0, 0, 0);
        }
    }

    // ---- shfl-reduce L2 norm + direct normalized stores ----
    {
        float ss[4];
        #pragma unroll
        for (int rr = 0; rr < 4; ++rr)
            ss[rr] = acc2[0][rr] * acc2[0][rr] + acc2[1][rr] * acc2[1][rr];
        #pragma unroll
        for (int mask = 1; mask <= 8; mask <<= 1) {
            #pragma unroll
            for (int rr = 0; rr < 4; ++rr) ss[rr] += __shfl_xor(ss[rr], mask);
        }
        if (m == 0) {
            #pragma unroll
            for (int rr = 0; rr < 4; ++rr) wsum[wv][q * 4 + rr] = ss[rr];
        }
    }
    __syncthreads();
    if (t < 16) {
        float tot = wsum[0][t] + wsum[1][t] + wsum[2][t] + wsum[3][t];
        rn[t] = 1.0f / fmaxf(sqrtf(tot), 1e-12f);
    }
    __syncthreads();
    {
        #pragma unroll
        for (int i = 0; i < 2; ++i) {
            int col = (ctbase + i) * 16 + m;
            #pragma unroll
            for (int rr = 0; rr < 4; ++rr) {
                int n = q * 4 + rr;
                out_desc[(size_t)(n0 + n) * CC + col] = acc2[i][rr] * rn[n];
            }
        }
    }
}

// ---------------------------------------------------------------------------
// Fallback: original fused baseline (used only if ws is too small).
__global__ __launch_bounds__(256, 4) void sddh_baseline(
    const float* __restrict__ x, const float* __restrict__ keypoints,
    const float* __restrict__ w1, const float* __restrict__ b1,
    const float* __restrict__ w2, const float* __restrict__ b2,
    const float* __restrict__ wsf, const float* __restrict__ agg,
    float* __restrict__ out_desc, float* __restrict__ out_off)
{
    const int bn = blockIdx.x;
    const int b  = bn / NN;
    const int t  = threadIdx.x;
    const float* xi = x + (size_t)b * CC * HWSZ;

    __shared__ float patch[CC * 9];
    __shared__ float conv_part[16][17];
    __shared__ float h1s[16];
    __shared__ float offs[16];
    __shared__ float feats[CC][NPOS];
    __shared__ float cpart2[CC][NPOS];
    __shared__ float g[CC][NPOS];
    __shared__ float dpart[CC];
    __shared__ float desc[CC];
    __shared__ float sq[128];
    __shared__ float kxy[2];

    if (t == 0) {
        float kx = keypoints[(size_t)bn * 2 + 0];
        float ky = keypoints[(size_t)bn * 2 + 1];
        kxy[0] = (kx * 0.5f + 0.5f) * (float)(WW - 1);
        kxy[1] = (ky * 0.5f + 0.5f) * (float)(HH - 1);
    }
    __syncthreads();
    const float kwx = kxy[0], kwy = kxy[1];
    const int rcx = (int)kwx, rcy = (int)kwy;
    int cx = (int)truncf((float)rcx - 0.5f);
    int cy = (int)truncf((float)rcy - 0.5f);
    cx = min(max(cx, 0), WW - 1 - KS);
    cy = min(max(cy, 0), HH - 1 - KS);

    for (int e = t; e < CC * 9; e += 256) {
        int c = e / 9, k = e % 9;
        int dy = k / 3, dx = k % 3;
        patch[e] = xi[(size_t)c * HWSZ + (cy + dy) * WW + (cx + dx)];
    }
    __syncthreads();
    {
        int o = t & 15, j = t >> 4;
        float acc = 0.f;
        const float* wo = w1 + o * (CC * 9);
        for (int e = j; e < CC * 9; e += 16) acc += patch[e] * wo[e];
        conv_part[o][j] = acc;
    }
    __syncthreads();
    if (t < 16) {
        float s = b1[t];
        #pragma unroll
        for (int j = 0; j < 16; j++) s += conv_part[t][j];
        h1s[t] = fmaxf(s, 0.f);
    }
    __syncthreads();
    if (t < 16) {
        float s = b2[t];
        #pragma unroll
        for (int k = 0; k < 16; k++) s += h1s[k] * w2[t * 16 + k];
        s = fminf(fmaxf(s, -MAX_OFFSET), MAX_OFFSET);
        offs[t] = s;
        int idx = (t < 8) ? (bn * 16 + t * 2) : (bn * 16 + (t - 8) * 2 + 1);
        out_off[idx] = s;
    }
    __syncthreads();

    for (int e = t; e < CC * NPOS; e += 256) {
        int c = e & 127, p = e >> 7;
        float px = kwx + offs[p];
        float py = kwy + offs[8 + p];
        float x0f = floorf(px), y0f = floorf(py);
        int x0 = (int)x0f, y0 = (int)y0f;
        float wx1 = px - x0f, wx0 = 1.f - wx1;
        float wy1 = py - y0f, wy0 = 1.f - wy1;
        const float* xc = xi + (size_t)c * HWSZ;
        int x0c = min(max(x0, 0), WW - 1);
        int x1c = min(max(x0 + 1, 0), WW - 1);
        int y0c = min(max(y0, 0), HH - 1);
        int y1c = min(max(y0 + 1, 0), HH - 1);
        float vx0 = (x0 >= 0 && x0 < WW) ? 1.f : 0.f;
        float vx1 = (x0 + 1 >= 0 && x0 + 1 < WW) ? 1.f : 0.f;
        float vy0 = (y0 >= 0 && y0 < HH) ? 1.f : 0.f;
        float vy1 = (y0 + 1 >= 0 && y0 + 1 < HH) ? 1.f : 0.f;
        float v = 0.f;
        v += xc[y0c * WW + x0c] * (wx0 * wy0) * (vx0 * vy0);
        v += xc[y0c * WW + x1c] * (wx1 * wy0) * (vx1 * vy0);
        v += xc[y1c * WW + x0c] * (wx0 * wy1) * (vx0 * vy1);
        v += xc[y1c * WW + x1c] * (wx1 * wy1) * (vx1 * vy1);
        feats[c][p] = v;
    }
    __syncthreads();
    {
        int d = t & 127, chalf = t >> 7;
        float acc[NPOS];
        #pragma unroll
        for (int p = 0; p < NPOS; p++) acc[p] = 0.f;
        const float* wrow = wsf + d * CC;
        int c0 = chalf * 64;
        for (int c = c0; c < c0 + 64; c++) {
            float wv = wrow[c];
            #pragma unroll
            for (int p = 0; p < NPOS; p++) acc[p] += feats[c][p] * wv;
        }
        if (chalf) {
            #pragma unroll
            for (int p = 0; p < NPOS; p++) cpart2[d][p] = acc[p];
        }
        __syncthreads();
        if (!chalf) {
            #pragma unroll
            for (int p = 0; p < NPOS; p++) {
                float s = acc[p] + cpart2[d][p];
                s = (s > 0.f) ? (SELU_SCALE * s)
                              : (SELU_SCALE * SELU_ALPHA * (expf(s) - 1.f));
                g[d][p] = s;
            }
        }
    }
    __syncthreads();
    {
        int d = t & 127, half = t >> 7;
        float acc = 0.f;
        int p0 = half * 4;
        for (int p = p0; p < p0 + 4; p++) {
            const float* ap = agg + (size_t)p * CC * CC;
            for (int e = 0; e < CC; e++) acc += g[e][p] * ap[e * CC + d];
        }
        if (half) dpart[d] = acc;
        __syncthreads();
        if (!half) {
            float v = acc + dpart[d];
            desc[d] = v;
            sq[d] = v * v;
        }
    }
    __syncthreads();
    if (t < 64) sq[t] += sq[t + 64]; __syncthreads();
    if (t < 32) sq[t] += sq[t + 32]; __syncthreads();
    if (t < 16) sq[t] += sq[t + 16]; __syncthreads();
    if (t < 8)  sq[t] += sq[t + 8];  __syncthreads();
    if (t < 4)  sq[t] += sq[t + 4];  __syncthreads();
    if (t < 2)  sq[t] += sq[t + 2];  __syncthreads();
    if (t == 0) sq[0] = fmaxf(sqrtf(sq[0] + sq[1]), 1e-12f);
    __syncthreads();
    if (t < 128) out_desc[(size_t)bn * CC + t] = desc[t] / sq[0];
}

// ---------------------------------------------------------------------------
extern "C" void kernel_launch(void* const* d_in, const int* in_sizes, int n_in,
                              void* d_out, int out_size, void* d_ws, size_t ws_size,
                              hipStream_t stream) {
    const float* x    = (const float*)d_in[0];
    const float* kpts = (const float*)d_in[1];
    const float* w1   = (const float*)d_in[2];
    const float* b1   = (const float*)d_in[3];
    const float* w2   = (const float*)d_in[4];
    const float* b2   = (const float*)d_in[5];
    const float* wsf  = (const float*)d_in[6];
    const float* agg  = (const float*)d_in[7];

    float* out_desc = (float*)d_out;
    float* out_off  = (float*)d_out + (size_t)BB * NN * CC;

    if (ws_size < WS_NEEDED) {
        hipLaunchKernelGGL(sddh_baseline, dim3(BB * NN), dim3(256), 0, stream,
                           x, kpts, w1, b1, w2, b2, wsf, agg, out_desc, out_off);
        return;
    }

    ushort_t* xt      = (ushort_t*)d_ws;
    ushort_t* wsf_bf  = xt + XT_ELEMS;
    ushort_t* aggT_bf = wsf_bf + WSFBF_ELEMS;
    ushort_t* w1t_bf  = aggT_bf + AGGT_ELEMS;

    hipLaunchKernelGGL(k0p, dim3(BB * HH * 4 + 512), dim3(256), 0, stream,
                       x, xt, wsf, agg, w1, wsf_bf, aggT_bf, w1t_bf);
    hipLaunchKernelGGL(k14_fused, dim3(BB * NN / 16), dim3(256), 0, stream,
                       xt, kpts, w1t_bf, b1, w2, b2, wsf_bf, aggT_bf,
                       out_desc, out_off);
}

// Round 9
// 101.580 us; speedup vs baseline: 1.1631x; 1.1049x over previous
//
#include <hip/hip_runtime.h>
#include <math.h>

#define BB 4
#define CC 128
#define HH 256
#define WW 256
#define NN 4000
#define NPOS 8
#define KS 3
#define HWSZ (HH*WW)

#define SELU_ALPHA 1.6732632423543772f
#define SELU_SCALE 1.0507009873554805f
#define MAX_OFFSET 64.0f

typedef unsigned short ushort_t;
typedef short short8 __attribute__((ext_vector_type(8)));
typedef float f32x4 __attribute__((ext_vector_type(4)));
typedef unsigned short ushort4_t __attribute__((ext_vector_type(4)));
typedef unsigned short ushort8_t __attribute__((ext_vector_type(8)));

#define XT_ELEMS    ((size_t)BB*HH*WW*CC)        // 33,554,432 bf16
#define WSFBF_ELEMS ((size_t)CC*CC)              // 16,384 bf16
#define AGGT_ELEMS  ((size_t)NPOS*CC*CC)         // 131,072 bf16
#define W1T_ELEMS   ((size_t)16*CC*9)            // 18,432 bf16
#define WS_NEEDED   ((XT_ELEMS+WSFBF_ELEMS+AGGT_ELEMS+W1T_ELEMS)*sizeof(ushort_t))

__device__ __forceinline__ ushort_t f2bf(float f) {
    unsigned u = __builtin_bit_cast(unsigned, f);
    unsigned r = (u + 0x7FFFu + ((u >> 16) & 1u)) >> 16;
    return (ushort_t)r;
}
__device__ __forceinline__ float bf2f(ushort_t u) {
    return __builtin_bit_cast(float, ((unsigned)u) << 16);
}

// ---------------------------------------------------------------------------
// K0P: transpose x (B,C,H,W) f32 -> xt (B,H,W,C) bf16; tail blocks do weight prep.
__global__ __launch_bounds__(256) void k0p(
    const float* __restrict__ x, ushort_t* __restrict__ xt,
    const float* __restrict__ wsf, const float* __restrict__ agg,
    const float* __restrict__ w1,
    ushort_t* __restrict__ wsf_bf, ushort_t* __restrict__ aggT_bf,
    ushort_t* __restrict__ w1t_bf)
{
    int blk = blockIdx.x;
    const int t = threadIdx.x;
    if (blk >= BB * HH * 4) {
        int i = (blk - BB * HH * 4) * 256 + t;
        if (i < CC * CC) wsf_bf[i] = f2bf(wsf[i]);
        if (i < NPOS * CC * CC) {
            int p = i >> 14, d = (i >> 7) & 127, c = i & 127;
            aggT_bf[i] = f2bf(agg[(p << 14) + (c << 7) + d]);
        }
        if (i < 16 * 1152) {
            int o = i / 1152, e = i - o * 1152, k = e >> 7, c = e & 127;
            w1t_bf[i] = f2bf(w1[o * 1152 + c * 9 + k]);
        }
        return;
    }
    int xc = blk & 3, y = (blk >> 2) & 255, b = blk >> 10;
    int x0 = xc * 64;
    __shared__ ushort_t lds[64][136];

    const float* xb = x + (size_t)b * CC * HWSZ + (size_t)y * WW + x0;
    for (int v = t; v < 2048; v += 256) {
        int c = v >> 4, xo4 = v & 15;
        float4 val = *(const float4*)(xb + (size_t)c * HWSZ + xo4 * 4);
        lds[xo4*4+0][c] = f2bf(val.x);
        lds[xo4*4+1][c] = f2bf(val.y);
        lds[xo4*4+2][c] = f2bf(val.z);
        lds[xo4*4+3][c] = f2bf(val.w);
    }
    __syncthreads();
    ushort_t* outb = xt + ((size_t)b * HWSZ + (size_t)y * WW + x0) * CC;
    for (int v = t; v < 2048; v += 256) {
        int xo = v >> 5, c4 = v & 31;
        ushort4_t val;
        val[0] = lds[xo][c4*4+0];
        val[1] = lds[xo][c4*4+1];
        val[2] = lds[xo][c4*4+2];
        val[3] = lds[xo][c4*4+3];
        *(ushort4_t*)(outb + (size_t)xo * CC + c4 * 4) = val;
    }
}

// ---------------------------------------------------------------------------
// K14 fused (R8 base + deep-preload gathers, launch_bounds(256,2)):
// conv(MFMA, A preloaded from global) -> FC offsets -> taps -> bilinear
// (16 lanes per (kp,p), 2 batches of 16 preloaded 16B tap rows) -> fg=feats
// (bf16, swz (r&7)<<4) -> GEMM-C in-place (selu -> fg=g) -> GEMM-D ->
// shfl-norm -> direct stores.  LDS 39.9KB still caps residency at 4 blocks/CU.
__global__ __launch_bounds__(256, 2) void k14_fused(
    const ushort_t* __restrict__ xt, const float* __restrict__ kpts,
    const ushort_t* __restrict__ w1t_bf, const float* __restrict__ b1,
    const float* __restrict__ w2, const float* __restrict__ b2,
    const ushort_t* __restrict__ wsf_bf, const ushort_t* __restrict__ aggT_bf,
    float* __restrict__ out_desc, float* __restrict__ out_off)
{
    const int t    = threadIdx.x;
    const int wv   = t >> 6;
    const int lane = t & 63;
    const int m    = lane & 15;
    const int q    = lane >> 4;
    const int n0   = blockIdx.x * 16;
    const int b    = n0 / NN;
    const ushort_t* xb = xt + (size_t)b * HWSZ * CC;

    __shared__ ushort_t fg[CC * CC];      // feats then g (aliased, row-local)
    union PT {
        float partials[4][16][16];        // phase 1
        struct { int tapoff[128][4]; float tapw[128][4]; } tp;  // phases 2-3
    };
    __shared__ PT    upt;
    __shared__ float h1f[16][17];
    __shared__ float offs[16][16];
    __shared__ float kw[16][2];
    __shared__ int   cxy[16][2];
    __shared__ float wsum[4][16];
    __shared__ float rn[16];

    // ---- phase 0: keypoint coords + patch corners ----
    if (t < 16) {
        float kx = kpts[(size_t)(n0 + t) * 2 + 0];
        float ky = kpts[(size_t)(n0 + t) * 2 + 1];
        float kwx = (kx * 0.5f + 0.5f) * (float)(WW - 1);
        float kwy = (ky * 0.5f + 0.5f) * (float)(HH - 1);
        kw[t][0] = kwx; kw[t][1] = kwy;
        int rcx = (int)kwx, rcy = (int)kwy;
        int cx = (int)truncf((float)rcx - 0.5f);
        int cy = (int)truncf((float)rcy - 0.5f);
        cxy[t][0] = min(max(cx, 0), WW - 1 - KS);
        cxy[t][1] = min(max(cy, 0), HH - 1 - KS);
    }
    __syncthreads();

    // ---- phase 1: conv via MFMA, A-fragments preloaded from global xt ----
    {
        int px0 = cxy[m][0], py0 = cxy[m][1];
        const ushort_t* brow = w1t_bf + m * 1152 + wv * 288 + q * 8;
        short8 a0, a1, a2, a3, a4, a5, a6, a7, a8;
        #define LOAD_A(idx, dst) { \
            int e = wv * 288 + (idx) * 32 + q * 8; \
            int k = e >> 7, c = e & 127; \
            int kd = k / 3, kx2 = k - kd * 3; \
            dst = *(const short8*)(xb + ((size_t)((py0 + kd) * WW + px0 + kx2)) * CC + c); }
        LOAD_A(0, a0) LOAD_A(1, a1) LOAD_A(2, a2) LOAD_A(3, a3) LOAD_A(4, a4)
        LOAD_A(5, a5) LOAD_A(6, a6) LOAD_A(7, a7) LOAD_A(8, a8)
        #undef LOAD_A
        f32x4 hacc = {0.f, 0.f, 0.f, 0.f};
        #define MF(idx, areg) { \
            short8 bfr = *(const short8*)(brow + (idx) * 32); \
            hacc = __builtin_amdgcn_mfma_f32_16x16x32_bf16(areg, bfr, hacc, 0, 0, 0); }
        MF(0, a0) MF(1, a1) MF(2, a2) MF(3, a3) MF(4, a4)
        MF(5, a5) MF(6, a6) MF(7, a7) MF(8, a8)
        #undef MF
        #pragma unroll
        for (int r = 0; r < 4; ++r) upt.partials[wv][q * 4 + r][m] = hacc[r];
    }
    __syncthreads();
    {   // reduce K-partials + bias + relu
        int kp = t >> 4, o = t & 15;
        float h = upt.partials[0][kp][o] + upt.partials[1][kp][o]
                + upt.partials[2][kp][o] + upt.partials[3][kp][o] + b1[o];
        h1f[kp][o] = fmaxf(h, 0.f);
    }
    __syncthreads();
    {   // FC: off[kp][j] = clip(h1 . w2[j] + b2[j])
        int kp = t >> 4, j = t & 15;
        float s = b2[j];
        #pragma unroll
        for (int o = 0; o < 16; ++o) s += h1f[kp][o] * w2[j * 16 + o];
        s = fminf(fmaxf(s, -MAX_OFFSET), MAX_OFFSET);
        offs[kp][j] = s;
        int p = j & 7, comp = j >> 3;
        out_off[((size_t)(n0 + kp) * 8 + p) * 2 + comp] = s;
    }
    __syncthreads();

    // ---- phase 2: tap coords/weights once per (kp,p) (taps alias partials) ----
    if (t < 128) {
        int kp = t >> 3, p = t & 7;
        float px = kw[kp][0] + offs[kp][p];
        float py = kw[kp][1] + offs[kp][8 + p];
        float x0f = floorf(px), y0f = floorf(py);
        int x0 = (int)x0f, y0 = (int)y0f;
        float wx1 = px - x0f, wx0 = 1.f - wx1;
        float wy1 = py - y0f, wy0 = 1.f - wy1;
        int x0c = min(max(x0, 0), WW - 1);
        int x1c = min(max(x0 + 1, 0), WW - 1);
        int y0c = min(max(y0, 0), HH - 1);
        int y1c = min(max(y0 + 1, 0), HH - 1);
        float vx0 = (x0 >= 0 && x0 < WW) ? 1.f : 0.f;
        float vx1 = (x0 + 1 >= 0 && x0 + 1 < WW) ? 1.f : 0.f;
        float vy0 = (y0 >= 0 && y0 < HH) ? 1.f : 0.f;
        float vy1 = (y0 + 1 >= 0 && y0 + 1 < HH) ? 1.f : 0.f;
        upt.tp.tapoff[t][0] = (y0c * WW + x0c) * CC;
        upt.tp.tapoff[t][1] = (y0c * WW + x1c) * CC;
        upt.tp.tapoff[t][2] = (y1c * WW + x0c) * CC;
        upt.tp.tapoff[t][3] = (y1c * WW + x1c) * CC;
        upt.tp.tapw[t][0] = wx0 * wy0 * vx0 * vy0;
        upt.tp.tapw[t][1] = wx1 * wy0 * vx1 * vy0;
        upt.tp.tapw[t][2] = wx0 * wy1 * vx0 * vy1;
        upt.tp.tapw[t][3] = wx1 * wy1 * vx1 * vy1;
    }
    __syncthreads();

    // ---- phase 3: bilinear, 16 lanes per (kp,p); 2 batches of 16 preloaded
    //      16B tap rows (deep MLP: 16 loads in flight per thread) ----
    {
        const int grp = t >> 4;        // 16 groups of 16 lanes
        const int cl  = t & 15;        // channel octet
        #pragma unroll
        for (int half = 0; half < 2; ++half) {
            ushort8_t tv0[4], tv1[4], tv2[4], tv3[4];
            float4 twv[4];
            #pragma unroll
            for (int i = 0; i < 4; ++i) {
                int pair = (half * 4 + i) * 16 + grp;
                const int* to = upt.tp.tapoff[pair];
                twv[i] = *(const float4*)upt.tp.tapw[pair];
                tv0[i] = *(const ushort8_t*)(xb + to[0] + cl * 8);
                tv1[i] = *(const ushort8_t*)(xb + to[1] + cl * 8);
                tv2[i] = *(const ushort8_t*)(xb + to[2] + cl * 8);
                tv3[i] = *(const ushort8_t*)(xb + to[3] + cl * 8);
            }
            #pragma unroll
            for (int i = 0; i < 4; ++i) {
                int pair = (half * 4 + i) * 16 + grp;
                float w00 = twv[i].x, w01 = twv[i].y, w10 = twv[i].z, w11 = twv[i].w;
                ushort8_t out;
                #pragma unroll
                for (int j = 0; j < 8; ++j) {
                    float v = bf2f(tv0[i][j]) * w00;
                    v += bf2f(tv1[i][j]) * w01;
                    v += bf2f(tv2[i][j]) * w10;
                    v += bf2f(tv3[i][j]) * w11;
                    out[j] = f2bf(v);
                }
                unsigned byte = ((unsigned)(pair * 256 + cl * 16))
                              ^ (((unsigned)(pair & 7)) << 4);
                *(ushort8_t*)((char*)fg + byte) = out;
            }
        }
    }
    __syncthreads();

    // ---- phase 4: GEMM-C (fg(feats) x wsf^T -> selu -> fg(g), in-place) ----
    for (int rti = 0; rti < 2; ++rti) {
        int rt = wv * 2 + rti;
        int r  = rt * 16 + m;
        unsigned key = ((unsigned)(r & 7)) << 4;
        short8 afr[4];
        #pragma unroll
        for (int kk = 0; kk < 4; ++kk) {
            unsigned byte = ((unsigned)(r * 256 + q * 16 + kk * 64)) ^ key;
            afr[kk] = *(const short8*)((const char*)fg + byte);
        }
        for (int ct = 0; ct < 8; ++ct) {
            const ushort_t* brow = wsf_bf + (ct * 16 + m) * CC + q * 8;
            f32x4 acc = {0.f, 0.f, 0.f, 0.f};
            #pragma unroll
            for (int kk = 0; kk < 4; ++kk) {
                short8 bfr = *(const short8*)(brow + kk * 32);
                acc = __builtin_amdgcn_mfma_f32_16x16x32_bf16(afr[kk], bfr, acc, 0, 0, 0);
            }
            #pragma unroll
            for (int rr = 0; rr < 4; ++rr) {
                float s = acc[rr];
                s = (s > 0.f) ? (SELU_SCALE * s)
                              : (SELU_SCALE * SELU_ALPHA * (expf(s) - 1.f));
                int row = rt * 16 + q * 4 + rr;     // same 16-row block as afr rows
                int col = ct * 16 + m;
                unsigned byte = ((unsigned)(row * 256 + col * 2))
                              ^ (((unsigned)((row >> 3) & 7)) << 4);
                *(ushort_t*)((char*)fg + byte) = f2bf(s);
            }
        }
    }
    __syncthreads();

    // ---- phase 5: GEMM-D (fg(g) x aggT) ----
    f32x4 acc2[2];
    acc2[0] = (f32x4){0.f, 0.f, 0.f, 0.f};
    acc2[1] = (f32x4){0.f, 0.f, 0.f, 0.f};
    const int ctbase = wv * 2;
    for (int kk = 0; kk < 32; ++kk) {
        int p    = kk >> 2;
        int rowA = m * 8 + p;
        unsigned byte = ((unsigned)(rowA * 256 + (kk & 3) * 64 + q * 16))
                      ^ (((unsigned)((rowA >> 3) & 7)) << 4);
        short8 afr = *(const short8*)((const char*)fg + byte);
        #pragma unroll
        for (int i = 0; i < 2; ++i) {
            int ct = ctbase + i;
            const ushort_t* brow = aggT_bf + (size_t)(p * CC + ct * 16 + m) * CC
                                 + (kk & 3) * 32 + q * 8;
            short8 bfr = *(const short8*)brow;
            acc2[i] = __builtin_amdgcn_mfma_f32_16x16x32_bf16(afr, bfr, acc2[i], 0, 0, 0);
        }
    }

    // ---- shfl-reduce L2 norm + direct normalized stores ----
    {
        float ss[4];
        #pragma unroll
        for (int rr = 0; rr < 4; ++rr)
            ss[rr] = acc2[0][rr] * acc2[0][rr] + acc2[1][rr] * acc2[1][rr];
        #pragma unroll
        for (int mask = 1; mask <= 8; mask <<= 1) {
            #pragma unroll
            for (int rr = 0; rr < 4; ++rr) ss[rr] += __shfl_xor(ss[rr], mask);
        }
        if (m == 0) {
            #pragma unroll
            for (int rr = 0; rr < 4; ++rr) wsum[wv][q * 4 + rr] = ss[rr];
        }
    }
    __syncthreads();
    if (t < 16) {
        float tot = wsum[0][t] + wsum[1][t] + wsum[2][t] + wsum[3][t];
        rn[t] = 1.0f / fmaxf(sqrtf(tot), 1e-12f);
    }
    __syncthreads();
    {
        #pragma unroll
        for (int i = 0; i < 2; ++i) {
            int col = (ctbase + i) * 16 + m;
            #pragma unroll
            for (int rr = 0; rr < 4; ++rr) {
                int n = q * 4 + rr;
                out_desc[(size_t)(n0 + n) * CC + col] = acc2[i][rr] * rn[n];
            }
        }
    }
}

// ---------------------------------------------------------------------------
// Fallback: original fused baseline (used only if ws is too small).
__global__ __launch_bounds__(256, 4) void sddh_baseline(
    const float* __restrict__ x, const float* __restrict__ keypoints,
    const float* __restrict__ w1, const float* __restrict__ b1,
    const float* __restrict__ w2, const float* __restrict__ b2,
    const float* __restrict__ wsf, const float* __restrict__ agg,
    float* __restrict__ out_desc, float* __restrict__ out_off)
{
    const int bn = blockIdx.x;
    const int b  = bn / NN;
    const int t  = threadIdx.x;
    const float* xi = x + (size_t)b * CC * HWSZ;

    __shared__ float patch[CC * 9];
    __shared__ float conv_part[16][17];
    __shared__ float h1s[16];
    __shared__ float offs[16];
    __shared__ float feats[CC][NPOS];
    __shared__ float cpart2[CC][NPOS];
    __shared__ float g[CC][NPOS];
    __shared__ float dpart[CC];
    __shared__ float desc[CC];
    __shared__ float sq[128];
    __shared__ float kxy[2];

    if (t == 0) {
        float kx = keypoints[(size_t)bn * 2 + 0];
        float ky = keypoints[(size_t)bn * 2 + 1];
        kxy[0] = (kx * 0.5f + 0.5f) * (float)(WW - 1);
        kxy[1] = (ky * 0.5f + 0.5f) * (float)(HH - 1);
    }
    __syncthreads();
    const float kwx = kxy[0], kwy = kxy[1];
    const int rcx = (int)kwx, rcy = (int)kwy;
    int cx = (int)truncf((float)rcx - 0.5f);
    int cy = (int)truncf((float)rcy - 0.5f);
    cx = min(max(cx, 0), WW - 1 - KS);
    cy = min(max(cy, 0), HH - 1 - KS);

    for (int e = t; e < CC * 9; e += 256) {
        int c = e / 9, k = e % 9;
        int dy = k / 3, dx = k % 3;
        patch[e] = xi[(size_t)c * HWSZ + (cy + dy) * WW + (cx + dx)];
    }
    __syncthreads();
    {
        int o = t & 15, j = t >> 4;
        float acc = 0.f;
        const float* wo = w1 + o * (CC * 9);
        for (int e = j; e < CC * 9; e += 16) acc += patch[e] * wo[e];
        conv_part[o][j] = acc;
    }
    __syncthreads();
    if (t < 16) {
        float s = b1[t];
        #pragma unroll
        for (int j = 0; j < 16; j++) s += conv_part[t][j];
        h1s[t] = fmaxf(s, 0.f);
    }
    __syncthreads();
    if (t < 16) {
        float s = b2[t];
        #pragma unroll
        for (int k = 0; k < 16; k++) s += h1s[k] * w2[t * 16 + k];
        s = fminf(fmaxf(s, -MAX_OFFSET), MAX_OFFSET);
        offs[t] = s;
        int idx = (t < 8) ? (bn * 16 + t * 2) : (bn * 16 + (t - 8) * 2 + 1);
        out_off[idx] = s;
    }
    __syncthreads();

    for (int e = t; e < CC * NPOS; e += 256) {
        int c = e & 127, p = e >> 7;
        float px = kwx + offs[p];
        float py = kwy + offs[8 + p];
        float x0f = floorf(px), y0f = floorf(py);
        int x0 = (int)x0f, y0 = (int)y0f;
        float wx1 = px - x0f, wx0 = 1.f - wx1;
        float wy1 = py - y0f, wy0 = 1.f - wy1;
        const float* xc = xi + (size_t)c * HWSZ;
        int x0c = min(max(x0, 0), WW - 1);
        int x1c = min(max(x0 + 1, 0), WW - 1);
        int y0c = min(max(y0, 0), HH - 1);
        int y1c = min(max(y0 + 1, 0), HH - 1);
        float vx0 = (x0 >= 0 && x0 < WW) ? 1.f : 0.f;
        float vx1 = (x0 + 1 >= 0 && x0 + 1 < WW) ? 1.f : 0.f;
        float vy0 = (y0 >= 0 && y0 < HH) ? 1.f : 0.f;
        float vy1 = (y0 + 1 >= 0 && y0 + 1 < HH) ? 1.f : 0.f;
        float v = 0.f;
        v += xc[y0c * WW + x0c] * (wx0 * wy0) * (vx0 * vy0);
        v += xc[y0c * WW + x1c] * (wx1 * wy0) * (vx1 * vy0);
        v += xc[y1c * WW + x0c] * (wx0 * wy1) * (vx0 * vy1);
        v += xc[y1c * WW + x1c] * (wx1 * wy1) * (vx1 * vy1);
        feats[c][p] = v;
    }
    __syncthreads();
    {
        int d = t & 127, chalf = t >> 7;
        float acc[NPOS];
        #pragma unroll
        for (int p = 0; p < NPOS; p++) acc[p] = 0.f;
        const float* wrow = wsf + d * CC;
        int c0 = chalf * 64;
        for (int c = c0; c < c0 + 64; c++) {
            float wv = wrow[c];
            #pragma unroll
            for (int p = 0; p < NPOS; p++) acc[p] += feats[c][p] * wv;
        }
        if (chalf) {
            #pragma unroll
            for (int p = 0; p < NPOS; p++) cpart2[d][p] = acc[p];
        }
        __syncthreads();
        if (!chalf) {
            #pragma unroll
            for (int p = 0; p < NPOS; p++) {
                float s = acc[p] + cpart2[d][p];
                s = (s > 0.f) ? (SELU_SCALE * s)
                              : (SELU_SCALE * SELU_ALPHA * (expf(s) - 1.f));
                g[d][p] = s;
            }
        }
    }
    __syncthreads();
    {
        int d = t & 127, half = t >> 7;
        float acc = 0.f;
        int p0 = half * 4;
        for (int p = p0; p < p0 + 4; p++) {
            const float* ap = agg + (size_t)p * CC * CC;
            for (int e = 0; e < CC; e++) acc += g[e][p] * ap[e * CC + d];
        }
        if (half) dpart[d] = acc;
        __syncthreads();
        if (!half) {
            float v = acc + dpart[d];
            desc[d] = v;
            sq[d] = v * v;
        }
    }
    __syncthreads();
    if (t < 64) sq[t] += sq[t + 64]; __syncthreads();
    if (t < 32) sq[t] += sq[t + 32]; __syncthreads();
    if (t < 16) sq[t] += sq[t + 16]; __syncthreads();
    if (t < 8)  sq[t] += sq[t + 8];  __syncthreads();
    if (t < 4)  sq[t] += sq[t + 4];  __syncthreads();
    if (t < 2)  sq[t] += sq[t + 2];  __syncthreads();
    if (t == 0) sq[0] = fmaxf(sqrtf(sq[0] + sq[1]), 1e-12f);
    __syncthreads();
    if (t < 128) out_desc[(size_t)bn * CC + t] = desc[t] / sq[0];
}

// ---------------------------------------------------------------------------
extern "C" void kernel_launch(void* const* d_in, const int* in_sizes, int n_in,
                              void* d_out, int out_size, void* d_ws, size_t ws_size,
                              hipStream_t stream) {
    const float* x    = (const float*)d_in[0];
    const float* kpts = (const float*)d_in[1];
    const float* w1   = (const float*)d_in[2];
    const float* b1   = (const float*)d_in[3];
    const float* w2   = (const float*)d_in[4];
    const float* b2   = (const float*)d_in[5];
    const float* wsf  = (const float*)d_in[6];
    const float* agg  = (const float*)d_in[7];

    float* out_desc = (float*)d_out;
    float* out_off  = (float*)d_out + (size_t)BB * NN * CC;

    if (ws_size < WS_NEEDED) {
        hipLaunchKernelGGL(sddh_baseline, dim3(BB * NN), dim3(256), 0, stream,
                           x, kpts, w1, b1, w2, b2, wsf, agg, out_desc, out_off);
        return;
    }

    ushort_t* xt      = (ushort_t*)d_ws;
    ushort_t* wsf_bf  = xt + XT_ELEMS;
    ushort_t* aggT_bf = wsf_bf + WSFBF_ELEMS;
    ushort_t* w1t_bf  = aggT_bf + AGGT_ELEMS;

    hipLaunchKernelGGL(k0p, dim3(BB * HH * 4 + 512), dim3(256), 0, stream,
                       x, xt, wsf, agg, w1, wsf_bf, aggT_bf, w1t_bf);
    hipLaunchKernelGGL(k14_fused, dim3(BB * NN / 16), dim3(256), 0, stream,
                       xt, kpts, w1t_bf, b1, w2, b2, wsf_bf, aggT_bf,
                       out_desc, out_off);
}